// Round 6
// baseline (1560.565 us; speedup 1.0000x reference)
//
#include <hip/hip_runtime.h>

// BatchableConstraintGNN on MI355X.
// pe-table -> emb -> CSR-by-dst build -> 3 fused layer kernels
// (edge-parallel LDS-atomic aggregation + mfma_f32_16x16x32_bf16) -> MLP head.

#define NN 60000
#define MM 60000
#define EE 24
#define TT 6
#define NTILES ((NN + 63) / 64)   // 938
#define SCH 2048
#define SNB ((NN + SCH - 1) / SCH)  // 30
#define CSRCAP 180

typedef unsigned short u16;
typedef unsigned int   u32;
typedef __attribute__((ext_vector_type(8))) short bf16x8;
typedef __attribute__((ext_vector_type(4))) float f32x4;

__constant__ int c_SRC[EE] = {0,1,2,1,2,0,4,5,0,1,2,3,0,4,2,4,3,4,0,5,3,5,2,5};
__constant__ int c_ELIST[TT][5] = {{1,4,8,13,19},{0,2,9,0,0},{3,5,10,15,23},
                                   {11,17,21,0,0},{7,12,14,16,0},{6,18,20,22,0}};
__constant__ int c_ECOUNT[TT] = {5,3,5,3,4,4};
__constant__ int c_TLIST[3][6] = {{0,1,2,3,4,5},{0,2,3,4,5,0},{4,5,0,0,0,0}};

__device__ __forceinline__ float lo16(u32 u){ union{u32 i; float f;} x; x.i = u << 16; return x.f; }
__device__ __forceinline__ float hi16(u32 u){ union{u32 i; float f;} x; x.i = u & 0xFFFF0000u; return x.f; }
__device__ __forceinline__ float bf2f(u16 u){ union{u32 i; float f;} x; x.i = (u32)u << 16; return x.f; }
__device__ __forceinline__ u16 f2bf(float f){
  union{float f; u32 i;} x; x.f = f;
  u32 r = (x.i + 0x7FFFu + ((x.i >> 16) & 1u)) >> 16;  // RNE
  return (u16)r;
}
__device__ __forceinline__ u32 pack2(float a, float b){ return (u32)f2bf(a) | ((u32)f2bf(b) << 16); }

// ---------------- weight prep ----------------
__global__ __launch_bounds__(256) void k_prep(const float* __restrict__ Wl, const float* __restrict__ bl,
                                              const float* __restrict__ Wr,
                                              u16* __restrict__ WlT, u16* __restrict__ WrTs,
                                              float* __restrict__ blsum)
{
  const int total1 = 3*EE*4096, total2 = 3*TT*4096, total3 = 3*TT*64;
  for (int i = blockIdx.x*blockDim.x + threadIdx.x; i < total1+total2+total3; i += gridDim.x*blockDim.x) {
    if (i < total1) {                    // WlT[l][e][ko][h] = Wl[l][e][h][ko]
      int h = i & 63, ko = (i >> 6) & 63, le = i >> 12;
      WlT[i] = f2bf(Wl[(size_t)le*4096 + h*64 + ko]);
    } else if (i < total1 + total2) {    // WrTs[l][t][ko][h] = sum_{e in dst(t)} Wr[l][e][h][ko]
      int j = i - total1;
      int h = j & 63, ko = (j >> 6) & 63, lt = j >> 12;
      int l = lt / TT, t = lt % TT;
      float s = 0.f;
      for (int q = 0; q < c_ECOUNT[t]; ++q) {
        int e = c_ELIST[t][q];
        s += Wr[((size_t)(l*EE + e)*64 + h)*64 + ko];
      }
      WrTs[j] = f2bf(s);
    } else {                             // blsum
      int j = i - total1 - total2;
      int k = j & 63, lt = j >> 6;
      int l = lt / TT, t = lt % TT;
      float s = 0.f;
      for (int q = 0; q < c_ECOUNT[t]; ++q) s += bl[(size_t)(l*EE + c_ELIST[t][q])*64 + k];
      blsum[j] = s;
    }
  }
}

// ---------------- positional-encoding table ----------------
__global__ __launch_bounds__(256) void k_pe(
    const int* __restrict__ tm0, const int* __restrict__ tm1,
    const int* __restrict__ tm2, const int* __restrict__ tm3,
    const int* __restrict__ tm4, const int* __restrict__ tm5,
    float4* __restrict__ pe)
{
  const int i = blockIdx.x*blockDim.x + threadIdx.x;
  if (i >= TT*NN) return;
  const int t = i / NN, n = i - t*NN;
  int tm;
  switch (t) {
    case 0:  tm = tm0[n]; break;
    case 1:  tm = tm1[n]; break;
    case 2:  tm = tm2[n]; break;
    case 3:  tm = tm3[n]; break;
    case 4:  tm = tm4[n]; break;
    default: tm = tm5[n]; break;
  }
  const float a0 = (float)tm, a1 = a0 * 0.01f;
  float4 v;
  v.x = sinf(a0); v.y = cosf(a0); v.z = sinf(a1); v.w = cosf(a1);
  pe[i] = v;
}

// ---------------- embeddings ----------------
__global__ __launch_bounds__(256) void k_embed(
    const float* __restrict__ x0, const float* __restrict__ x1,
    const float* __restrict__ x2, const float* __restrict__ x3,
    const float4* __restrict__ pe,
    const float* __restrict__ W0, const float* __restrict__ b0,
    const float* __restrict__ W1, const float* __restrict__ b1,
    const float* __restrict__ W2, const float* __restrict__ b2,
    const float* __restrict__ W3, const float* __restrict__ b3,
    const float* __restrict__ W4, const float* __restrict__ b4,
    const float* __restrict__ W5, const float* __restrict__ b5,
    u16* __restrict__ X)
{
  const int tid = threadIdx.x;
  const int t = blockIdx.y;
  const int n = blockIdx.x * 4 + (tid >> 6);
  const int k = tid & 63;
  const float4 p = pe[(size_t)t*NN + n];
  const float p0 = p.x, p1 = p.y, p2 = p.z, p3 = p.w;
  float acc;
  if (t == 0) {
    const float* x = x0 + (size_t)n*4;
    acc = b0[k] + x[0]*W0[k] + x[1]*W0[64+k] + x[2]*W0[128+k] + x[3]*W0[192+k]
        + p0*W0[256+k] + p1*W0[320+k] + p2*W0[384+k] + p3*W0[448+k];
  } else if (t == 1) {
    const float* x = x1 + (size_t)n*4;
    acc = b1[k] + x[0]*W1[k] + x[1]*W1[64+k] + x[2]*W1[128+k] + x[3]*W1[192+k]
        + p0*W1[256+k] + p1*W1[320+k] + p2*W1[384+k] + p3*W1[448+k];
  } else if (t == 2) {
    const float* x = x2 + (size_t)n*4;
    acc = b2[k] + x[0]*W2[k] + x[1]*W2[64+k] + x[2]*W2[128+k] + x[3]*W2[192+k]
        + p0*W2[256+k] + p1*W2[320+k] + p2*W2[384+k] + p3*W2[448+k];
  } else if (t == 3) {
    const float* x = x3 + (size_t)n*3;
    acc = b3[k] + x[0]*W3[k] + x[1]*W3[64+k] + x[2]*W3[128+k]
        + p0*W3[192+k] + p1*W3[256+k] + p2*W3[320+k] + p3*W3[384+k];
  } else if (t == 4) {
    acc = b4[k] + p0*W4[k] + p1*W4[64+k] + p2*W4[128+k] + p3*W4[192+k];
  } else {
    acc = b5[k] + p0*W5[k] + p1*W5[64+k] + p2*W5[128+k] + p3*W5[192+k];
  }
  X[((size_t)t*NN + n)*64 + k] = f2bf(acc);
}

// ---------------- CSR build ----------------
__global__ __launch_bounds__(256) void k_count(const int* __restrict__ ei, int* __restrict__ counts) {
  for (int i = blockIdx.x*blockDim.x + threadIdx.x; i < EE*MM; i += gridDim.x*blockDim.x) {
    int e = i / MM, m = i - e*MM;
    int d = ei[(size_t)e*2*MM + MM + m];
    atomicAdd(&counts[(size_t)e*NN + d], 1);
  }
}

__global__ __launch_bounds__(256) void k_scan1(const int* __restrict__ counts, int* __restrict__ ctot) {
  const int e = blockIdx.y, ch = blockIdx.x;
  const int tid = threadIdx.x, lane = tid & 63, wid = tid >> 6;
  __shared__ int ws[4];
  int s = 0;
  for (int i = tid; i < SCH; i += 256) {
    int n = ch*SCH + i;
    if (n < NN) s += counts[(size_t)e*NN + n];
  }
  #pragma unroll
  for (int d = 1; d < 64; d <<= 1) s += __shfl_xor(s, d);
  if (lane == 0) ws[wid] = s;
  __syncthreads();
  if (tid == 0) ctot[e*SNB + ch] = ws[0] + ws[1] + ws[2] + ws[3];
}

__global__ __launch_bounds__(64) void k_scan2(int* __restrict__ ctot) {
  const int e = blockIdx.x, lane = threadIdx.x;
  int v = (lane < SNB) ? ctot[e*SNB + lane] : 0;
  int s = v;
  #pragma unroll
  for (int d = 1; d < 64; d <<= 1) { int u = __shfl_up(s, d); if (lane >= d) s += u; }
  if (lane < SNB) ctot[e*SNB + lane] = s - v;
}

__global__ __launch_bounds__(256) void k_scan3(const int* __restrict__ counts, const int* __restrict__ ctot,
                                               int* __restrict__ offs) {
  const int e = blockIdx.y, ch = blockIdx.x;
  const int tid = threadIdx.x, lane = tid & 63, wid = tid >> 6;
  __shared__ int ws[4];
  __shared__ int cbase;
  if (tid == 0) cbase = ctot[e*SNB + ch];
  __syncthreads();
  for (int i0 = 0; i0 < SCH; i0 += 256) {
    const int n = ch*SCH + i0 + tid;
    const int c = (n < NN) ? counts[(size_t)e*NN + n] : 0;
    int s = c;
    #pragma unroll
    for (int d = 1; d < 64; d <<= 1) { int u = __shfl_up(s, d); if (lane >= d) s += u; }
    if (lane == 63) ws[wid] = s;
    __syncthreads();
    int wbase = 0;
    for (int q = 0; q < wid; ++q) wbase += ws[q];
    if (n < NN) offs[(size_t)e*(NN+1) + n] = cbase + wbase + s - c;
    __syncthreads();
    if (tid == 0) cbase += ws[0] + ws[1] + ws[2] + ws[3];
    __syncthreads();
  }
  if (ch == SNB-1 && tid == 0) offs[(size_t)e*(NN+1) + NN] = cbase;
}

__global__ __launch_bounds__(256) void k_place(const int* __restrict__ ei, const int* __restrict__ offs,
                                               int* __restrict__ counts, int* __restrict__ csr) {
  for (int i = blockIdx.x*blockDim.x + threadIdx.x; i < EE*MM; i += gridDim.x*blockDim.x) {
    int e = i / MM, m = i - e*MM;
    int s = ei[(size_t)e*2*MM + m];
    int d = ei[(size_t)e*2*MM + MM + m];
    int old = atomicSub(&counts[(size_t)e*NN + d], 1);
    csr[(size_t)e*MM + offs[(size_t)e*(NN+1) + d] + old - 1] = s;
  }
}

// ---------------- fused layer kernel ----------------
struct WB { int offs_w[65]; int csr_w[CSRCAP]; };

__device__ __forceinline__ void mm_tile(f32x4 acc[4], const u16* la, const u16* lb, int lane, int w)
{
  const int arow = w*16 + (lane & 15);
  const int kel  = (lane >> 4) * 8;
  #pragma unroll
  for (int kb = 0; kb < 2; ++kb) {
    bf16x8 a = *(const bf16x8*)&la[arow*72 + kb*32 + kel];
    #pragma unroll
    for (int nt = 0; nt < 4; ++nt) {
      bf16x8 b = *(const bf16x8*)&lb[(nt*16 + (lane & 15))*72 + kb*32 + kel];
      acc[nt] = __builtin_amdgcn_mfma_f32_16x16x32_bf16(a, b, acc[nt], 0, 0, 0);
    }
  }
}

__global__ __launch_bounds__(256) void k_layer(
    const u16* __restrict__ Xin, u16* __restrict__ Xout,
    const int* __restrict__ offs, const int* __restrict__ csr,
    const u16* __restrict__ WlT, const u16* __restrict__ WrTs,
    const float* __restrict__ blsum, float* __restrict__ gemb, int l)
{
  __shared__ __align__(16) u16 lds_a[64*72];
  __shared__ __align__(16) u16 lds_b[64*72];
  __shared__ __align__(16) float aggf[64*68];   // f32 agg tile, pad 68 (16B-aligned rows per quarter)
  __shared__ WB wbuf[2];
  __shared__ int ph_beg[8], ph_cnt[8];

  const int tid  = threadIdx.x;
  const int tile = blockIdx.x % NTILES;
  const int t    = c_TLIST[l][blockIdx.x / NTILES];
  const int n0   = tile * 64;
  const int lane = tid & 63;
  const int w    = tid >> 6;
  const int ec   = c_ECOUNT[t];

  // per-phase [beg,end)
  if (tid < ec) {
    const int e2 = c_ELIST[t][tid];
    int hi = n0 + 64; if (hi > NN) hi = NN;
    int b  = offs[(size_t)e2*(NN+1) + n0];
    int en = offs[(size_t)e2*(NN+1) + hi];
    ph_beg[tid+1] = b; ph_cnt[tid+1] = en - b;
  }

  // zero the f32 agg tile once (re-zeroed during pack each phase)
  {
    float4 z = {0.f,0.f,0.f,0.f};
    float4* az = (float4*)aggf;
    for (int i = tid; i < 64*68/4; i += 256) az[i] = z;
  }
  __syncthreads();

  auto stage_win = [&](int qp) {
    if (qp > ec) return;
    const int e2 = c_ELIST[t][qp-1];
    WB* w2 = &wbuf[qp & 1];
    const int beg2 = ph_beg[qp], cnt2 = ph_cnt[qp];
    if (tid < 65) {
      int idx = n0 + tid; if (idx > NN) idx = NN;
      w2->offs_w[tid] = offs[(size_t)e2*(NN+1) + idx] - beg2;
    }
    const int lim = cnt2 < CSRCAP ? cnt2 : CSRCAP;
    for (int i = tid; i < lim; i += 256) w2->csr_w[i] = csr[(size_t)e2*MM + beg2 + i];
  };

  f32x4 acc[4];
  #pragma unroll
  for (int i = 0; i < 4; ++i) acc[i] = (f32x4){0.f,0.f,0.f,0.f};

  // section 0: self term X[t] @ WrSum^T (+ prefetch window 1)
  {
    stage_win(1);
    const int r = tid >> 2, h0 = (tid & 3) * 16;
    const int n = n0 + r;
    uint4 v0 = {0,0,0,0}, v1 = {0,0,0,0};
    if (n < NN) {
      const uint4* p = (const uint4*)(Xin + ((size_t)t*NN + n)*64 + h0);
      v0 = p[0]; v1 = p[1];
    }
    *(uint4*)&lds_a[r*72 + h0]     = v0;
    *(uint4*)&lds_a[r*72 + h0 + 8] = v1;
    const uint4* q = (const uint4*)(WrTs + (size_t)(l*TT + t)*4096 + r*64 + h0);
    uint4 w0 = q[0], w1 = q[1];
    *(uint4*)&lds_b[r*72 + h0]     = w0;
    *(uint4*)&lds_b[r*72 + h0 + 8] = w1;
  }
  __syncthreads();
  mm_tile(acc, lds_a, lds_b, lane, w);

  for (int qq = 1; qq <= ec; ++qq) {
    const int e = c_ELIST[t][qq-1];
    const int s = c_SRC[e];
    __syncthreads();                   // (A) prev mm done; aggf zeroed
    stage_win(qq + 1);
    // edge-parallel aggregate: 8 lanes/edge, 32 edges per block-iteration
    {
      const WB* wb = &wbuf[qq & 1];
      const int beg = ph_beg[qq], cnt = ph_cnt[qq];
      const int h0 = (tid & 7) * 8;    // 8 bf16 = 16B slice of the row
      const int eb = tid >> 3;         // 0..31
      const u16* Xs = Xin + (size_t)s * NN * 64;
      const bool inLds = (cnt <= CSRCAP);
      for (int jb = 0; jb < cnt; jb += 32) {
        const int j = jb + eb;
        if (j < cnt) {
          const int sn = inLds ? wb->csr_w[j] : csr[(size_t)e*MM + beg + j];
          const uint4 v = *(const uint4*)(Xs + (size_t)sn*64 + h0);
          int lo = 0, hi = 64;         // bsearch dst row: offs_w[lo] <= j < offs_w[lo+1]
          #pragma unroll
          for (int st = 0; st < 6; ++st) {
            const int mid = (lo + hi) >> 1;
            const bool ge = (wb->offs_w[mid] <= j);
            lo = ge ? mid : lo;
            hi = ge ? hi : mid;
          }
          float* ap = &aggf[lo*68 + h0];
          atomicAdd(ap+0, lo16(v.x)); atomicAdd(ap+1, hi16(v.x));
          atomicAdd(ap+2, lo16(v.y)); atomicAdd(ap+3, hi16(v.y));
          atomicAdd(ap+4, lo16(v.z)); atomicAdd(ap+5, hi16(v.z));
          atomicAdd(ap+6, lo16(v.w)); atomicAdd(ap+7, hi16(v.w));
        }
      }
    }
    // stage B = WlT[l][e] (independent; must land before barrier C)
    {
      const int r2 = tid >> 2, g0 = (tid & 3) * 16;
      const uint4* p = (const uint4*)(WlT + (size_t)(l*EE + e)*4096 + r2*64 + g0);
      uint4 w0 = p[0], w1 = p[1];
      *(uint4*)&lds_b[r2*72 + g0]     = w0;
      *(uint4*)&lds_b[r2*72 + g0 + 8] = w1;
    }
    __syncthreads();                   // (B) aggf complete
    // pack aggf -> lds_a bf16 (scale by 1/deg) and re-zero aggf
    {
      const WB* wb = &wbuf[qq & 1];
      const int r = tid >> 2, g0 = (tid & 3) * 16;
      const int deg = wb->offs_w[r+1] - wb->offs_w[r];
      const float rd = 1.0f / (float)(deg > 1 ? deg : 1);
      float4* ap4 = (float4*)&aggf[r*68 + g0];
      float4 b0 = ap4[0], b1 = ap4[1], b2 = ap4[2], b3 = ap4[3];
      float4 z = {0.f,0.f,0.f,0.f};
      ap4[0] = z; ap4[1] = z; ap4[2] = z; ap4[3] = z;
      uint4 s0, s1;
      s0.x = pack2(b0.x*rd, b0.y*rd); s0.y = pack2(b0.z*rd, b0.w*rd);
      s0.z = pack2(b1.x*rd, b1.y*rd); s0.w = pack2(b1.z*rd, b1.w*rd);
      s1.x = pack2(b2.x*rd, b2.y*rd); s1.y = pack2(b2.z*rd, b2.w*rd);
      s1.z = pack2(b3.x*rd, b3.y*rd); s1.w = pack2(b3.z*rd, b3.w*rd);
      *(uint4*)&lds_a[r*72 + g0]     = s0;
      *(uint4*)&lds_a[r*72 + g0 + 8] = s1;
    }
    __syncthreads();                   // (C) lds_a, lds_b ready
    mm_tile(acc, lds_a, lds_b, lane, w);
  }

  // epilogue
  __syncthreads();
  {
    const int col = lane & 15;
    const int rb  = w*16 + ((lane >> 4) << 2);
    #pragma unroll
    for (int nt = 0; nt < 4; ++nt) {
      const float blv = blsum[(size_t)(l*TT + t)*64 + nt*16 + col];
      #pragma unroll
      for (int j = 0; j < 4; ++j) {
        const float v = fmaxf(acc[nt][j] + blv, 0.f);
        const int rl = rb + j;
        lds_a[rl*72 + nt*16 + col] = ((n0 + rl) < NN) ? f2bf(v) : (u16)0;
      }
    }
  }
  __syncthreads();
  if (l < 2) {
    const int r = tid >> 2, h0 = (tid & 3) * 16;
    const int n = n0 + r;
    if (n < NN) {
      uint4 v0 = *(const uint4*)&lds_a[r*72 + h0];
      uint4 v1 = *(const uint4*)&lds_a[r*72 + h0 + 8];
      uint4* dst = (uint4*)(Xout + ((size_t)t*NN + n)*64 + h0);
      dst[0] = v0; dst[1] = v1;
    }
  } else if (tid < 64) {
    float sm = 0.f;
    for (int r = 0; r < 64; ++r) sm += bf2f(lds_a[r*72 + tid]);
    atomicAdd(&gemb[tid], sm);
  }
}

// ---------------- scalar head ----------------
__global__ void k_head(const float* __restrict__ gemb, const float* __restrict__ Wm1,
                       const float* __restrict__ bm1, const float* __restrict__ Wm2,
                       const float* __restrict__ bm2, float* __restrict__ out)
{
  __shared__ float h[64];
  __shared__ float h2[16];
  const int tid = threadIdx.x;
  if (tid < 64) h[tid] = fmaxf(gemb[tid], 0.f);
  __syncthreads();
  if (tid < 16) {
    float a = bm1[tid];
    for (int i = 0; i < 64; ++i) a += h[i] * Wm1[i*16 + tid];
    h2[tid] = fmaxf(a, 0.f);
  }
  __syncthreads();
  if (tid == 0) {
    float a = bm2[0];
    for (int j = 0; j < 16; ++j) a += h2[j] * Wm2[j];
    out[0] = a;
  }
}

extern "C" void kernel_launch(void* const* d_in, const int* in_sizes, int n_in,
                              void* d_out, int out_size, void* d_ws, size_t ws_size,
                              hipStream_t stream) {
  char* ws = (char*)d_ws;
  size_t off = 0;
  auto take = [&](size_t bytes) -> char* {
    char* p = ws + off;
    off += (bytes + 255) & ~(size_t)255;
    return p;
  };
  u16*   XA     = (u16*)  take((size_t)6*NN*64*2);
  u16*   XB     = (u16*)  take((size_t)6*NN*64*2);
  u16*   WlT    = (u16*)  take((size_t)3*EE*4096*2);
  u16*   WrTs   = (u16*)  take((size_t)3*TT*4096*2);
  float* blsum  = (float*)take((size_t)3*TT*64*4);
  int*   counts = (int*)  take((size_t)EE*NN*4);
  int*   offs   = (int*)  take((size_t)EE*(NN+1)*4);
  int*   csr    = (int*)  take((size_t)EE*MM*4);
  int*   ctot   = (int*)  take((size_t)EE*SNB*4);
  float* petab  = (float*)take((size_t)TT*NN*16);
  float* gemb   = (float*)take(64*4);
  (void)ws_size; (void)in_sizes; (void)n_in; (void)out_size;

  hipMemsetAsync(counts, 0, (size_t)EE*NN*4, stream);
  hipMemsetAsync(gemb, 0, 64*4, stream);

  const float* Wl = (const float*)d_in[23];
  const float* bl = (const float*)d_in[24];
  const float* Wr = (const float*)d_in[25];

  k_prep<<<512, 256, 0, stream>>>(Wl, bl, Wr, WlT, WrTs, blsum);

  k_pe<<<(TT*NN + 255)/256, 256, 0, stream>>>(
      (const int*)d_in[4], (const int*)d_in[5], (const int*)d_in[6],
      (const int*)d_in[7], (const int*)d_in[8], (const int*)d_in[9],
      (float4*)petab);

  k_embed<<<dim3(NN/4, 6), 256, 0, stream>>>(
      (const float*)d_in[0], (const float*)d_in[1], (const float*)d_in[2], (const float*)d_in[3],
      (const float4*)petab,
      (const float*)d_in[11], (const float*)d_in[12],
      (const float*)d_in[13], (const float*)d_in[14],
      (const float*)d_in[15], (const float*)d_in[16],
      (const float*)d_in[17], (const float*)d_in[18],
      (const float*)d_in[19], (const float*)d_in[20],
      (const float*)d_in[21], (const float*)d_in[22],
      XA);

  const int* ei = (const int*)d_in[10];
  k_count<<<2048, 256, 0, stream>>>(ei, counts);
  k_scan1<<<dim3(SNB, EE), 256, 0, stream>>>(counts, ctot);
  k_scan2<<<EE, 64, 0, stream>>>(ctot);
  k_scan3<<<dim3(SNB, EE), 256, 0, stream>>>(counts, ctot, offs);
  k_place<<<2048, 256, 0, stream>>>(ei, offs, counts, csr);

  k_layer<<<NTILES*6, 256, 0, stream>>>(XA, XB, offs, csr, WlT, WrTs, blsum, gemb, 0);
  k_layer<<<NTILES*5, 256, 0, stream>>>(XB, XA, offs, csr, WlT, WrTs, blsum, gemb, 1);
  k_layer<<<NTILES*2, 256, 0, stream>>>(XA, XB, offs, csr, WlT, WrTs, blsum, gemb, 2);

  k_head<<<1, 64, 0, stream>>>(gemb, (const float*)d_in[26], (const float*)d_in[27],
                               (const float*)d_in[28], (const float*)d_in[29], (float*)d_out);
}

// Round 8
// 528.236 us; speedup vs baseline: 2.9543x; 2.9543x over previous
//
#include <hip/hip_runtime.h>

// BatchableConstraintGNN on MI355X.
// k_init (weights-prep + pe-table + zeroing) -> emb -> CSR-by-dst build ->
// 3 fused layer kernels (LDS-windowed CSR gather, 2-slot load pipeline,
// mfma_f32_16x16x32_bf16) -> scalar MLP head.

#define NN 60000
#define MM 60000
#define EE 24
#define TT 6
#define NTILES ((NN + 63) / 64)   // 938
#define SCH 2048
#define SNB ((NN + SCH - 1) / SCH)  // 30
#define CSRCAP 180

typedef unsigned short u16;
typedef unsigned int   u32;
typedef __attribute__((ext_vector_type(8))) short bf16x8;
typedef __attribute__((ext_vector_type(4))) float f32x4;

__constant__ int c_SRC[EE] = {0,1,2,1,2,0,4,5,0,1,2,3,0,4,2,4,3,4,0,5,3,5,2,5};
__constant__ int c_ELIST[TT][5] = {{1,4,8,13,19},{0,2,9,0,0},{3,5,10,15,23},
                                   {11,17,21,0,0},{7,12,14,16,0},{6,18,20,22,0}};
__constant__ int c_ECOUNT[TT] = {5,3,5,3,4,4};
__constant__ int c_TLIST[3][6] = {{0,1,2,3,4,5},{0,2,3,4,5,0},{4,5,0,0,0,0}};

__device__ __forceinline__ float lo16(u32 u){ union{u32 i; float f;} x; x.i = u << 16; return x.f; }
__device__ __forceinline__ float hi16(u32 u){ union{u32 i; float f;} x; x.i = u & 0xFFFF0000u; return x.f; }
__device__ __forceinline__ float bf2f(u16 u){ union{u32 i; float f;} x; x.i = (u32)u << 16; return x.f; }
__device__ __forceinline__ u16 f2bf(float f){
  union{float f; u32 i;} x; x.f = f;
  u32 r = (x.i + 0x7FFFu + ((x.i >> 16) & 1u)) >> 16;  // RNE
  return (u16)r;
}
__device__ __forceinline__ u32 pack2(float a, float b){ return (u32)f2bf(a) | ((u32)f2bf(b) << 16); }

// ---------------- fused init: weight prep + pe table + zero counts/gemb ----------------
__global__ __launch_bounds__(256) void k_init(
    const float* __restrict__ Wl, const float* __restrict__ bl, const float* __restrict__ Wr,
    const int* __restrict__ tm0, const int* __restrict__ tm1,
    const int* __restrict__ tm2, const int* __restrict__ tm3,
    const int* __restrict__ tm4, const int* __restrict__ tm5,
    u16* __restrict__ WlT, u16* __restrict__ WrTs, float* __restrict__ blsum,
    float4* __restrict__ pe, int* __restrict__ counts, float* __restrict__ gemb)
{
  const int total1 = 3*EE*4096;            // WlT transpose
  const int total2 = 3*TT*4096;            // WrTs
  const int total3 = 3*TT*64;              // blsum
  const int total4 = TT*NN;                // pe table
  const int total5 = EE*NN;                // zero counts
  const int T12 = total1 + total2;
  const int T13 = T12 + total3;
  const int T14 = T13 + total4;
  const int T15 = T14 + total5;
  const int total = T15 + 64;
  for (int i = blockIdx.x*blockDim.x + threadIdx.x; i < total; i += gridDim.x*blockDim.x) {
    if (i < total1) {                      // WlT[l][e][ko][h] = Wl[l][e][h][ko]
      int h = i & 63, ko = (i >> 6) & 63, le = i >> 12;
      WlT[i] = f2bf(Wl[(size_t)le*4096 + h*64 + ko]);
    } else if (i < T12) {                  // WrTs[l][t][ko][h] = sum_{e in dst(t)} Wr[l][e][h][ko]
      int j = i - total1;
      int h = j & 63, ko = (j >> 6) & 63, lt = j >> 12;
      int l = lt / TT, t = lt % TT;
      float s = 0.f;
      for (int q = 0; q < c_ECOUNT[t]; ++q) {
        int e = c_ELIST[t][q];
        s += Wr[((size_t)(l*EE + e)*64 + h)*64 + ko];
      }
      WrTs[j] = f2bf(s);
    } else if (i < T13) {                  // blsum
      int j = i - T12;
      int k = j & 63, lt = j >> 6;
      int l = lt / TT, t = lt % TT;
      float s = 0.f;
      for (int q = 0; q < c_ECOUNT[t]; ++q) s += bl[(size_t)(l*EE + c_ELIST[t][q])*64 + k];
      blsum[j] = s;
    } else if (i < T14) {                  // pe[t][n]
      int j = i - T13;
      int t = j / NN, n = j - t*NN;
      int tm;
      switch (t) {
        case 0:  tm = tm0[n]; break;
        case 1:  tm = tm1[n]; break;
        case 2:  tm = tm2[n]; break;
        case 3:  tm = tm3[n]; break;
        case 4:  tm = tm4[n]; break;
        default: tm = tm5[n]; break;
      }
      const float a0 = (float)tm, a1 = a0 * 0.01f;
      float4 v;
      v.x = sinf(a0); v.y = cosf(a0); v.z = sinf(a1); v.w = cosf(a1);
      pe[j] = v;
    } else if (i < T15) {
      counts[i - T14] = 0;
    } else {
      gemb[i - T15] = 0.f;
    }
  }
}

// ---------------- embeddings ----------------
__global__ __launch_bounds__(256) void k_embed(
    const float* __restrict__ x0, const float* __restrict__ x1,
    const float* __restrict__ x2, const float* __restrict__ x3,
    const float4* __restrict__ pe,
    const float* __restrict__ W0, const float* __restrict__ b0,
    const float* __restrict__ W1, const float* __restrict__ b1,
    const float* __restrict__ W2, const float* __restrict__ b2,
    const float* __restrict__ W3, const float* __restrict__ b3,
    const float* __restrict__ W4, const float* __restrict__ b4,
    const float* __restrict__ W5, const float* __restrict__ b5,
    u16* __restrict__ X)
{
  const int tid = threadIdx.x;
  const int t = blockIdx.y;
  const int n = blockIdx.x * 4 + (tid >> 6);
  const int k = tid & 63;
  const float4 p = pe[(size_t)t*NN + n];
  const float p0 = p.x, p1 = p.y, p2 = p.z, p3 = p.w;
  float acc;
  if (t == 0) {
    const float* x = x0 + (size_t)n*4;
    acc = b0[k] + x[0]*W0[k] + x[1]*W0[64+k] + x[2]*W0[128+k] + x[3]*W0[192+k]
        + p0*W0[256+k] + p1*W0[320+k] + p2*W0[384+k] + p3*W0[448+k];
  } else if (t == 1) {
    const float* x = x1 + (size_t)n*4;
    acc = b1[k] + x[0]*W1[k] + x[1]*W1[64+k] + x[2]*W1[128+k] + x[3]*W1[192+k]
        + p0*W1[256+k] + p1*W1[320+k] + p2*W1[384+k] + p3*W1[448+k];
  } else if (t == 2) {
    const float* x = x2 + (size_t)n*4;
    acc = b2[k] + x[0]*W2[k] + x[1]*W2[64+k] + x[2]*W2[128+k] + x[3]*W2[192+k]
        + p0*W2[256+k] + p1*W2[320+k] + p2*W2[384+k] + p3*W2[448+k];
  } else if (t == 3) {
    const float* x = x3 + (size_t)n*3;
    acc = b3[k] + x[0]*W3[k] + x[1]*W3[64+k] + x[2]*W3[128+k]
        + p0*W3[192+k] + p1*W3[256+k] + p2*W3[320+k] + p3*W3[384+k];
  } else if (t == 4) {
    acc = b4[k] + p0*W4[k] + p1*W4[64+k] + p2*W4[128+k] + p3*W4[192+k];
  } else {
    acc = b5[k] + p0*W5[k] + p1*W5[64+k] + p2*W5[128+k] + p3*W5[192+k];
  }
  X[((size_t)t*NN + n)*64 + k] = f2bf(acc);
}

// ---------------- CSR build ----------------
__global__ __launch_bounds__(256) void k_count(const int* __restrict__ ei, int* __restrict__ counts) {
  for (int i = blockIdx.x*blockDim.x + threadIdx.x; i < EE*MM; i += gridDim.x*blockDim.x) {
    int e = i / MM, m = i - e*MM;
    int d = ei[(size_t)e*2*MM + MM + m];
    atomicAdd(&counts[(size_t)e*NN + d], 1);
  }
}

__global__ __launch_bounds__(256) void k_scan1(const int* __restrict__ counts, int* __restrict__ ctot) {
  const int e = blockIdx.y, ch = blockIdx.x;
  const int tid = threadIdx.x, lane = tid & 63, wid = tid >> 6;
  __shared__ int ws[4];
  int s = 0;
  for (int i = tid; i < SCH; i += 256) {
    int n = ch*SCH + i;
    if (n < NN) s += counts[(size_t)e*NN + n];
  }
  #pragma unroll
  for (int d = 1; d < 64; d <<= 1) s += __shfl_xor(s, d);
  if (lane == 0) ws[wid] = s;
  __syncthreads();
  if (tid == 0) ctot[e*SNB + ch] = ws[0] + ws[1] + ws[2] + ws[3];
}

__global__ __launch_bounds__(64) void k_scan2(int* __restrict__ ctot) {
  const int e = blockIdx.x, lane = threadIdx.x;
  int v = (lane < SNB) ? ctot[e*SNB + lane] : 0;
  int s = v;
  #pragma unroll
  for (int d = 1; d < 64; d <<= 1) { int u = __shfl_up(s, d); if (lane >= d) s += u; }
  if (lane < SNB) ctot[e*SNB + lane] = s - v;
}

__global__ __launch_bounds__(256) void k_scan3(const int* __restrict__ counts, const int* __restrict__ ctot,
                                               int* __restrict__ offs) {
  const int e = blockIdx.y, ch = blockIdx.x;
  const int tid = threadIdx.x, lane = tid & 63, wid = tid >> 6;
  __shared__ int ws[4];
  __shared__ int cbase;
  if (tid == 0) cbase = ctot[e*SNB + ch];
  __syncthreads();
  for (int i0 = 0; i0 < SCH; i0 += 256) {
    const int n = ch*SCH + i0 + tid;
    const int c = (n < NN) ? counts[(size_t)e*NN + n] : 0;
    int s = c;
    #pragma unroll
    for (int d = 1; d < 64; d <<= 1) { int u = __shfl_up(s, d); if (lane >= d) s += u; }
    if (lane == 63) ws[wid] = s;
    __syncthreads();
    int wbase = 0;
    for (int q = 0; q < wid; ++q) wbase += ws[q];
    if (n < NN) offs[(size_t)e*(NN+1) + n] = cbase + wbase + s - c;
    __syncthreads();
    if (tid == 0) cbase += ws[0] + ws[1] + ws[2] + ws[3];
    __syncthreads();
  }
  if (ch == SNB-1 && tid == 0) offs[(size_t)e*(NN+1) + NN] = cbase;
}

__global__ __launch_bounds__(256) void k_place(const int* __restrict__ ei, const int* __restrict__ offs,
                                               int* __restrict__ counts, int* __restrict__ csr) {
  for (int i = blockIdx.x*blockDim.x + threadIdx.x; i < EE*MM; i += gridDim.x*blockDim.x) {
    int e = i / MM, m = i - e*MM;
    int s = ei[(size_t)e*2*MM + m];
    int d = ei[(size_t)e*2*MM + MM + m];
    int old = atomicSub(&counts[(size_t)e*NN + d], 1);
    csr[(size_t)e*MM + offs[(size_t)e*(NN+1) + d] + old - 1] = s;
  }
}

// ---------------- fused layer kernel ----------------
struct WB { int offs_w[65]; int csr_w[CSRCAP]; };

__device__ __forceinline__ void mm_tile(f32x4 acc[4], const u16* la, const u16* lb, int lane, int w)
{
  const int arow = w*16 + (lane & 15);
  const int kel  = (lane >> 4) * 8;
  #pragma unroll
  for (int kb = 0; kb < 2; ++kb) {
    bf16x8 a = *(const bf16x8*)&la[arow*72 + kb*32 + kel];
    #pragma unroll
    for (int nt = 0; nt < 4; ++nt) {
      bf16x8 b = *(const bf16x8*)&lb[(nt*16 + (lane & 15))*72 + kb*32 + kel];
      acc[nt] = __builtin_amdgcn_mfma_f32_16x16x32_bf16(a, b, acc[nt], 0, 0, 0);
    }
  }
}

__global__ __launch_bounds__(256) void k_layer(
    const u16* __restrict__ Xin, u16* __restrict__ Xout,
    const int* __restrict__ offs, const int* __restrict__ csr,
    const u16* __restrict__ WlT, const u16* __restrict__ WrTs,
    const float* __restrict__ blsum, float* __restrict__ gemb, int l)
{
  __shared__ __align__(16) u16 lds_a[64*72];
  __shared__ __align__(16) u16 lds_b[64*72];
  __shared__ WB wbuf[2];
  __shared__ int ph_beg[8], ph_cnt[8];

  const int tid  = threadIdx.x;
  const int tile = blockIdx.x % NTILES;
  const int t    = c_TLIST[l][blockIdx.x / NTILES];
  const int n0   = tile * 64;
  const int lane = tid & 63;
  const int w    = tid >> 6;
  const int ec   = c_ECOUNT[t];

  // prefetch per-phase [beg,end) once
  if (tid < ec) {
    const int e2 = c_ELIST[t][tid];
    int hi = n0 + 64; if (hi > NN) hi = NN;
    int b  = offs[(size_t)e2*(NN+1) + n0];
    int en = offs[(size_t)e2*(NN+1) + hi];
    ph_beg[tid+1] = b; ph_cnt[tid+1] = en - b;
  }
  __syncthreads();

  // stage offs/csr windows (coalesced) for phase qp into wbuf[qp&1]
  auto stage_win = [&](int qp) {
    if (qp > ec) return;
    const int e2 = c_ELIST[t][qp-1];
    WB* w2 = &wbuf[qp & 1];
    const int beg2 = ph_beg[qp], cnt2 = ph_cnt[qp];
    if (tid < 65) {
      int idx = n0 + tid; if (idx > NN) idx = NN;
      w2->offs_w[tid] = offs[(size_t)e2*(NN+1) + idx] - beg2;
    }
    const int lim = cnt2 < CSRCAP ? cnt2 : CSRCAP;
    for (int i = tid; i < lim; i += 256) w2->csr_w[i] = csr[(size_t)e2*MM + beg2 + i];
  };

  f32x4 acc[4];
  #pragma unroll
  for (int i = 0; i < 4; ++i) acc[i] = (f32x4){0.f,0.f,0.f,0.f};

  // section 0: stage self A (X[t] tile) + B (WrSum^T) + windows(1)
  {
    stage_win(1);
    const int r = tid >> 2, h0 = (tid & 3) * 16;
    const int n = n0 + r;
    uint4 v0 = {0,0,0,0}, v1 = {0,0,0,0};
    if (n < NN) {
      const uint4* p = (const uint4*)(Xin + ((size_t)t*NN + n)*64 + h0);
      v0 = p[0]; v1 = p[1];
    }
    *(uint4*)&lds_a[r*72 + h0]     = v0;
    *(uint4*)&lds_a[r*72 + h0 + 8] = v1;
    const uint4* q = (const uint4*)(WrTs + (size_t)(l*TT + t)*4096 + r*64 + h0);
    uint4 w0 = q[0], w1 = q[1];
    *(uint4*)&lds_b[r*72 + h0]     = w0;
    *(uint4*)&lds_b[r*72 + h0 + 8] = w1;
  }
  __syncthreads();
  mm_tile(acc, lds_a, lds_b, lane, w);

  for (int qq = 1; qq <= ec; ++qq) {
    const int e = c_ELIST[t][qq-1];
    const int s = c_SRC[e];
    __syncthreads();                   // prev mm done with lds tiles & window
    stage_win(qq + 1);
    // gather: 4 lanes per row, one pass over 64 rows, 2-slot alternating
    // load pipeline (no register copies -> ~2 outstanding loads per lane)
    {
      const WB* wb = &wbuf[qq & 1];
      const int beg = ph_beg[qq], cnt = ph_cnt[qq];
      const int r = tid >> 2;
      const int h0 = (tid & 3) * 16;
      const int n = n0 + r;
      const u16* Xs = Xin + (size_t)s * NN * 64;
      float a[16];
      #pragma unroll
      for (int i = 0; i < 16; ++i) a[i] = 0.f;
      if (n < NN) {
        const int b  = wb->offs_w[r];
        const int en = wb->offs_w[r+1];
        if (cnt <= CSRCAP) {
          uint4 A0, A1, B0, B1;
          int j = b;
          if (j < en) {
            const u16* xp = Xs + (size_t)wb->csr_w[j]*64 + h0;
            A0 = *(const uint4*)xp; A1 = *(const uint4*)(xp + 8);
          }
          if (j + 1 < en) {
            const u16* xp = Xs + (size_t)wb->csr_w[j+1]*64 + h0;
            B0 = *(const uint4*)xp; B1 = *(const uint4*)(xp + 8);
          }
          while (j < en) {
            // consume slot A (waits only on A), then reissue A <- j+2
            a[0]+=lo16(A0.x); a[1]+=hi16(A0.x); a[2]+=lo16(A0.y); a[3]+=hi16(A0.y);
            a[4]+=lo16(A0.z); a[5]+=hi16(A0.z); a[6]+=lo16(A0.w); a[7]+=hi16(A0.w);
            a[8]+=lo16(A1.x); a[9]+=hi16(A1.x); a[10]+=lo16(A1.y); a[11]+=hi16(A1.y);
            a[12]+=lo16(A1.z); a[13]+=hi16(A1.z); a[14]+=lo16(A1.w); a[15]+=hi16(A1.w);
            if (j + 2 < en) {
              const u16* xp = Xs + (size_t)wb->csr_w[j+2]*64 + h0;
              A0 = *(const uint4*)xp; A1 = *(const uint4*)(xp + 8);
            }
            if (j + 1 < en) {
              // consume slot B, reissue B <- j+3
              a[0]+=lo16(B0.x); a[1]+=hi16(B0.x); a[2]+=lo16(B0.y); a[3]+=hi16(B0.y);
              a[4]+=lo16(B0.z); a[5]+=hi16(B0.z); a[6]+=lo16(B0.w); a[7]+=hi16(B0.w);
              a[8]+=lo16(B1.x); a[9]+=hi16(B1.x); a[10]+=lo16(B1.y); a[11]+=hi16(B1.y);
              a[12]+=lo16(B1.z); a[13]+=hi16(B1.z); a[14]+=lo16(B1.w); a[15]+=hi16(B1.w);
              if (j + 3 < en) {
                const u16* xp = Xs + (size_t)wb->csr_w[j+3]*64 + h0;
                B0 = *(const uint4*)xp; B1 = *(const uint4*)(xp + 8);
              }
            }
            j += 2;
          }
        } else {                                // overflow fallback (never in practice)
          for (int j = b; j < en; ++j) {
            int sn = csr[(size_t)e*MM + beg + j];
            const u16* xp = Xs + (size_t)sn*64 + h0;
            uint4 c0 = *(const uint4*)xp, c1 = *(const uint4*)(xp + 8);
            a[0]+=lo16(c0.x); a[1]+=hi16(c0.x); a[2]+=lo16(c0.y); a[3]+=hi16(c0.y);
            a[4]+=lo16(c0.z); a[5]+=hi16(c0.z); a[6]+=lo16(c0.w); a[7]+=hi16(c0.w);
            a[8]+=lo16(c1.x); a[9]+=hi16(c1.x); a[10]+=lo16(c1.y); a[11]+=hi16(c1.y);
            a[12]+=lo16(c1.z); a[13]+=hi16(c1.z); a[14]+=lo16(c1.w); a[15]+=hi16(c1.w);
          }
        }
        const int d = en - b;
        const float rd = 1.0f / (float)(d > 1 ? d : 1);
        #pragma unroll
        for (int i = 0; i < 16; ++i) a[i] *= rd;
      }
      uint4 s0, s1;
      s0.x = pack2(a[0],a[1]);   s0.y = pack2(a[2],a[3]);
      s0.z = pack2(a[4],a[5]);   s0.w = pack2(a[6],a[7]);
      s1.x = pack2(a[8],a[9]);   s1.y = pack2(a[10],a[11]);
      s1.z = pack2(a[12],a[13]); s1.w = pack2(a[14],a[15]);
      *(uint4*)&lds_a[r*72 + h0]     = s0;
      *(uint4*)&lds_a[r*72 + h0 + 8] = s1;
    }
    // stage B = WlT[l][e]
    {
      const int r2 = tid >> 2, g0 = (tid & 3) * 16;
      const uint4* p = (const uint4*)(WlT + (size_t)(l*EE + e)*4096 + r2*64 + g0);
      uint4 w0 = p[0], w1 = p[1];
      *(uint4*)&lds_b[r2*72 + g0]     = w0;
      *(uint4*)&lds_b[r2*72 + g0 + 8] = w1;
    }
    __syncthreads();
    mm_tile(acc, lds_a, lds_b, lane, w);
  }

  // epilogue
  __syncthreads();
  {
    const int col = lane & 15;
    const int rb  = w*16 + ((lane >> 4) << 2);
    #pragma unroll
    for (int nt = 0; nt < 4; ++nt) {
      const float blv = blsum[(size_t)(l*TT + t)*64 + nt*16 + col];
      #pragma unroll
      for (int j = 0; j < 4; ++j) {
        const float v = fmaxf(acc[nt][j] + blv, 0.f);
        const int rl = rb + j;
        lds_a[rl*72 + nt*16 + col] = ((n0 + rl) < NN) ? f2bf(v) : (u16)0;
      }
    }
  }
  __syncthreads();
  if (l < 2) {
    const int r = tid >> 2, h0 = (tid & 3) * 16;
    const int n = n0 + r;
    if (n < NN) {
      uint4 v0 = *(const uint4*)&lds_a[r*72 + h0];
      uint4 v1 = *(const uint4*)&lds_a[r*72 + h0 + 8];
      uint4* dst = (uint4*)(Xout + ((size_t)t*NN + n)*64 + h0);
      dst[0] = v0; dst[1] = v1;
    }
  } else if (tid < 64) {
    float sm = 0.f;
    for (int r = 0; r < 64; ++r) sm += bf2f(lds_a[r*72 + tid]);
    atomicAdd(&gemb[tid], sm);
  }
}

// ---------------- scalar head ----------------
__global__ void k_head(const float* __restrict__ gemb, const float* __restrict__ Wm1,
                       const float* __restrict__ bm1, const float* __restrict__ Wm2,
                       const float* __restrict__ bm2, float* __restrict__ out)
{
  __shared__ float h[64];
  __shared__ float h2[16];
  const int tid = threadIdx.x;
  if (tid < 64) h[tid] = fmaxf(gemb[tid], 0.f);
  __syncthreads();
  if (tid < 16) {
    float a = bm1[tid];
    for (int i = 0; i < 64; ++i) a += h[i] * Wm1[i*16 + tid];
    h2[tid] = fmaxf(a, 0.f);
  }
  __syncthreads();
  if (tid == 0) {
    float a = bm2[0];
    for (int j = 0; j < 16; ++j) a += h2[j] * Wm2[j];
    out[0] = a;
  }
}

extern "C" void kernel_launch(void* const* d_in, const int* in_sizes, int n_in,
                              void* d_out, int out_size, void* d_ws, size_t ws_size,
                              hipStream_t stream) {
  char* ws = (char*)d_ws;
  size_t off = 0;
  auto take = [&](size_t bytes) -> char* {
    char* p = ws + off;
    off += (bytes + 255) & ~(size_t)255;
    return p;
  };
  u16*   XA     = (u16*)  take((size_t)6*NN*64*2);
  u16*   XB     = (u16*)  take((size_t)6*NN*64*2);
  u16*   WlT    = (u16*)  take((size_t)3*EE*4096*2);
  u16*   WrTs   = (u16*)  take((size_t)3*TT*4096*2);
  float* blsum  = (float*)take((size_t)3*TT*64*4);
  int*   counts = (int*)  take((size_t)EE*NN*4);
  int*   offs   = (int*)  take((size_t)EE*(NN+1)*4);
  int*   csr    = (int*)  take((size_t)EE*MM*4);
  int*   ctot   = (int*)  take((size_t)EE*SNB*4);
  float* petab  = (float*)take((size_t)TT*NN*16);
  float* gemb   = (float*)take(64*4);
  (void)ws_size; (void)in_sizes; (void)n_in; (void)out_size;

  const float* Wl = (const float*)d_in[23];
  const float* bl = (const float*)d_in[24];
  const float* Wr = (const float*)d_in[25];

  k_init<<<2048, 256, 0, stream>>>(
      Wl, bl, Wr,
      (const int*)d_in[4], (const int*)d_in[5], (const int*)d_in[6],
      (const int*)d_in[7], (const int*)d_in[8], (const int*)d_in[9],
      WlT, WrTs, blsum, (float4*)petab, counts, gemb);

  k_embed<<<dim3(NN/4, 6), 256, 0, stream>>>(
      (const float*)d_in[0], (const float*)d_in[1], (const float*)d_in[2], (const float*)d_in[3],
      (const float4*)petab,
      (const float*)d_in[11], (const float*)d_in[12],
      (const float*)d_in[13], (const float*)d_in[14],
      (const float*)d_in[15], (const float*)d_in[16],
      (const float*)d_in[17], (const float*)d_in[18],
      (const float*)d_in[19], (const float*)d_in[20],
      (const float*)d_in[21], (const float*)d_in[22],
      XA);

  const int* ei = (const int*)d_in[10];
  k_count<<<2048, 256, 0, stream>>>(ei, counts);
  k_scan1<<<dim3(SNB, EE), 256, 0, stream>>>(counts, ctot);
  k_scan2<<<EE, 64, 0, stream>>>(ctot);
  k_scan3<<<dim3(SNB, EE), 256, 0, stream>>>(counts, ctot, offs);
  k_place<<<2048, 256, 0, stream>>>(ei, offs, counts, csr);

  k_layer<<<NTILES*6, 256, 0, stream>>>(XA, XB, offs, csr, WlT, WrTs, blsum, gemb, 0);
  k_layer<<<NTILES*5, 256, 0, stream>>>(XB, XA, offs, csr, WlT, WrTs, blsum, gemb, 1);
  k_layer<<<NTILES*2, 256, 0, stream>>>(XA, XB, offs, csr, WlT, WrTs, blsum, gemb, 2);

  k_head<<<1, 64, 0, stream>>>(gemb, (const float*)d_in[26], (const float*)d_in[27],
                               (const float*)d_in[28], (const float*)d_in[29], (float*)d_out);
}